// Round 8
// baseline (478.513 us; speedup 1.0000x reference)
//
#include <hip/hip_runtime.h>
#include <math.h>

#define N_NODES 50000
#define N_EDGES 800000
#define N_GRAPHS 512
#define SLOPE 0.2f
#define CAP 48   // bucket capacity; degrees ~Poisson(16), P(deg>48)~1e-11
static constexpr float EPS_BN = 1e-5f;
static constexpr unsigned MAXOFF = (N_NODES - 1) * 64;  // clamp for garbage-slot gathers

typedef float v2f __attribute__((ext_vector_type(2)));

// ---------------- fused bucket-scatter + layer-0 transform (known-good t9) ----------
// ~57 us = atomic-chain floor at max TLP (tested EPT 1/2/4); accepted.

__global__ __launch_bounds__(256) void scatter_t9_kernel(
    const int* __restrict__ src, const int* __restrict__ dst,
    const float* __restrict__ ea,
    int* __restrict__ cnt, float4* __restrict__ rec,
    const float* __restrict__ x,
    const float* __restrict__ Wl0, const float* __restrict__ bl0,
    const float* __restrict__ Wr0, const float* __restrict__ br0,
    float* __restrict__ xl, float* __restrict__ xr) {
    int t = threadIdx.x;
    int e = blockIdx.x * 256 + t;
    if (e < N_EDGES) {
        int d = dst[e];
        int pos = atomicAdd(&cnt[d], 1);
        if (pos < CAP)
            rec[(size_t)d * CAP + pos] = make_float4(__int_as_float(src[e] * 64),
                                                     ea[e * 3 + 0], ea[e * 3 + 1], ea[e * 3 + 2]);
    }

    int w = t >> 6;
    int k = t & 63;
    v2f wlr[9];
#pragma unroll
    for (int j = 0; j < 9; j++) wlr[j] = (v2f){Wl0[j * 64 + k], Wr0[j * 64 + k]};
    v2f bias = {bl0[k], br0[k]};
    const int NW = gridDim.x * 4;
    for (int n = blockIdx.x * 4 + w; n < N_NODES; n += NW) {
        int un = __builtin_amdgcn_readfirstlane(n);
        const float* __restrict__ hrow = x + (size_t)un * 9;
        float hb[9];
#pragma unroll
        for (int j = 0; j < 9; j++) hb[j] = hrow[j];
        v2f acc = bias;
#pragma unroll
        for (int j = 0; j < 9; j++)
            acc = __builtin_elementwise_fma((v2f){hb[j], hb[j]}, wlr[j], acc);
        xl[(size_t)un * 64 + k] = acc.x;
        xr[(size_t)un * 64 + k] = acc.y;
    }
}

// ---------------- fused GATv2 + NEXT-LAYER transform epilogue ----------------------
// R7 postmortem fixes: (1) hT kk-major [8][64] -> h-row write is one contiguous
// ds_write_b128 (conflict-free; old transposed layout was 8-way = 3.19M conflict
// cycles/dispatch); mini-GEMM reads become uniform scalar broadcasts (free).
// (2) grid 768->2048: one 8-node batch per wave (was 2.03 -> 50% tail imbalance).

#define EDGE_T(rX, xXa, xXb, accX)                                        \
    {                                                                     \
        v2f tXa = xXa + xra, tXb = xXb + xrb;                             \
        tXa = __builtin_elementwise_fma((v2f){rX.y, rX.y}, we0a, tXa);    \
        tXb = __builtin_elementwise_fma((v2f){rX.y, rX.y}, we0b, tXb);    \
        tXa = __builtin_elementwise_fma((v2f){rX.z, rX.z}, we1a, tXa);    \
        tXb = __builtin_elementwise_fma((v2f){rX.z, rX.z}, we1b, tXb);    \
        tXa = __builtin_elementwise_fma((v2f){rX.w, rX.w}, we2a, tXa);    \
        tXb = __builtin_elementwise_fma((v2f){rX.w, rX.w}, we2b, tXb);    \
        tXa = __builtin_elementwise_max(tXa, tXa * SLOPE);                \
        tXb = __builtin_elementwise_max(tXb, tXb * SLOPE);                \
        v2f dX = ata * tXa;                                               \
        dX = __builtin_elementwise_fma(atb, tXb, dX);                     \
        accX = dX.x + dX.y;                                               \
    }

#define MMROW(kk, hv)                                                              \
    acc[kk][0] = __builtin_elementwise_fma((v2f){hv, hv}, w0, acc[kk][0]);         \
    acc[kk][1] = __builtin_elementwise_fma((v2f){hv, hv}, w1, acc[kk][1]);

__global__ __launch_bounds__(256) void gat_fusedT_kernel(
    const float* __restrict__ xl, const float* __restrict__ xr,
    const float4* __restrict__ recP, const int* __restrict__ cnt,
    const float* __restrict__ We, const float* __restrict__ att,
    const float* __restrict__ bo,
    const float* __restrict__ bn_g, const float* __restrict__ bn_b,
    const float* __restrict__ bn_m, const float* __restrict__ bn_v,
    const float* __restrict__ Wln, const float* __restrict__ bln,
    const float* __restrict__ Wrn, const float* __restrict__ brn,
    float* __restrict__ xln, float* __restrict__ xrn) {
    __shared__ float sW[2][64][68];   // next-layer Wl/Wr, pad 68 (34816 B)
    __shared__ float hT[4][8][64];    // per-wave h rows, kk-major (8192 B)
    int t = threadIdx.x;
    int w = t >> 6;
    int lane = t & 63;
    int q = lane >> 4;
    int r = lane & 15;
    int k4 = r * 4;

    // stage next-layer weights once per block
    for (int i = t; i < 2048; i += 256) {
        int mt = i >> 10;
        int j  = (i >> 4) & 63;
        int fc = i & 15;
        const float* Wsrc = mt ? Wrn : Wln;
        *((float4*)&sW[mt][j][fc * 4]) = *((const float4*)(Wsrc + j * 64 + fc * 4));
    }
    __syncthreads();

    float4 we0 = *(const float4*)(We + 0 * 64 + k4);
    float4 we1 = *(const float4*)(We + 64 + k4);
    float4 we2 = *(const float4*)(We + 128 + k4);
    float4 at4 = *(const float4*)(att + k4);
    v2f we0a = {we0.x, we0.y}, we0b = {we0.z, we0.w};
    v2f we1a = {we1.x, we1.y}, we1b = {we1.z, we1.w};
    v2f we2a = {we2.x, we2.y}, we2b = {we2.z, we2.w};
    v2f ata  = {at4.x, at4.y}, atb  = {at4.z, at4.w};
    float4 bo4 = *(const float4*)(bo + k4);
    float4 g4  = *(const float4*)(bn_g + k4);
    float4 b4  = *(const float4*)(bn_b + k4);
    float4 m4  = *(const float4*)(bn_m + k4);
    float4 v4  = *(const float4*)(bn_v + k4);
    float4 S, C;
    S.x = g4.x / sqrtf(v4.x + EPS_BN);  C.x = (bo4.x - m4.x) * S.x + b4.x;
    S.y = g4.y / sqrtf(v4.y + EPS_BN);  C.y = (bo4.y - m4.y) * S.y + b4.y;
    S.z = g4.z / sqrtf(v4.z + EPS_BN);  C.z = (bo4.z - m4.z) * S.z + b4.z;
    S.w = g4.w / sqrtf(v4.w + EPS_BN);  C.w = (bo4.w - m4.w) * S.w + b4.w;

    const int mat = q >> 1, jh = q & 1;

    const int NW = gridDim.x * 4;
    for (int b0 = blockIdx.x * 4 + w; b0 < N_NODES; b0 += NW * 8) {
        int kmax = 0;
        // ---- gat for up to 8 nodes; h rows -> hT[w][kk][*] ----
#pragma unroll 1
        for (int kk = 0; kk < 8; kk++) {
            int nn = b0 + kk * NW;
            if (nn >= N_NODES) break;
            kmax = kk + 1;
            int n = __builtin_amdgcn_readfirstlane(nn);
            int beg = n * CAP;
            int end = beg + min(cnt[n], CAP);
            float4 xq = *(const float4*)(xr + (size_t)n * 64 + k4);
            v2f xra = {xq.x, xq.y}, xrb = {xq.z, xq.w};

            // prologue: rec loads unguarded (recP has 16 slack records);
            // garbage offsets clamped, garbage lanes masked at exp (select).
            float4 cA0 = recP[beg + q];
            float4 cB0 = recP[beg + 4 + q];
            float4 cA1 = recP[beg + 8 + q];
            float4 cB1 = recP[beg + 12 + q];
            bool wA0 = (beg + q) < end,      wB0 = (beg + 4 + q) < end;
            bool wA1 = (beg + 8 + q) < end,  wB1 = (beg + 12 + q) < end;
            float4 gA0 = *(const float4*)(xl + (min((unsigned)__float_as_int(cA0.x), MAXOFF) + k4));
            float4 gB0 = *(const float4*)(xl + (min((unsigned)__float_as_int(cB0.x), MAXOFF) + k4));

            v2f oAa = {0.f, 0.f}, oAb = {0.f, 0.f};
            v2f oBa = {0.f, 0.f}, oBb = {0.f, 0.f};
            float zA = 0.f, zB = 0.f;

            int c = beg;
            while (c < end) {
                float4 gA1 = *(const float4*)(xl + (min((unsigned)__float_as_int(cA1.x), MAXOFF) + k4));
                float4 gB1 = *(const float4*)(xl + (min((unsigned)__float_as_int(cB1.x), MAXOFF) + k4));
                float4 cA2 = recP[c + 16 + q];
                float4 cB2 = recP[c + 20 + q];
                bool wA2 = (c + 16 + q) < end, wB2 = (c + 20 + q) < end;

                v2f xAa = {gA0.x, gA0.y}, xAb = {gA0.z, gA0.w};
                v2f xBa = {gB0.x, gB0.y}, xBb = {gB0.z, gB0.w};

                float accA, accB;
                EDGE_T(cA0, xAa, xAb, accA);
                EDGE_T(cB0, xBa, xBb, accB);

                accA += __shfl_xor(accA, 1, 64);  accB += __shfl_xor(accB, 1, 64);
                accA += __shfl_xor(accA, 2, 64);  accB += __shfl_xor(accB, 2, 64);
                accA += __shfl_xor(accA, 4, 64);  accB += __shfl_xor(accB, 4, 64);
                accA += __shfl_xor(accA, 8, 64);  accB += __shfl_xor(accB, 8, 64);

                float peA = wA0 ? __expf(accA) : 0.f;
                float peB = wB0 ? __expf(accB) : 0.f;
                v2f pAv = {peA, peA}, pBv = {peB, peB};
                oAa = __builtin_elementwise_fma(pAv, xAa, oAa);
                oAb = __builtin_elementwise_fma(pAv, xAb, oAb);
                oBa = __builtin_elementwise_fma(pBv, xBa, oBa);
                oBb = __builtin_elementwise_fma(pBv, xBb, oBb);
                zA += peA; zB += peB;

                cA0 = cA1; cB0 = cB1; wA0 = wA1; wB0 = wB1;
                cA1 = cA2; cB1 = cB2; wA1 = wA2; wB1 = wB2;
                gA0 = gA1; gB0 = gB1;
                c += 8;
            }

            v2f oa = oAa + oBa, ob = oAb + oBb;
            float z = zA + zB;
            float4 o = make_float4(oa.x, oa.y, ob.x, ob.y);
            o.x += __shfl_xor(o.x, 16, 64); o.x += __shfl_xor(o.x, 32, 64);
            o.y += __shfl_xor(o.y, 16, 64); o.y += __shfl_xor(o.y, 32, 64);
            o.z += __shfl_xor(o.z, 16, 64); o.z += __shfl_xor(o.z, 32, 64);
            o.w += __shfl_xor(o.w, 16, 64); o.w += __shfl_xor(o.w, 32, 64);
            z += __shfl_xor(z, 16, 64); z += __shfl_xor(z, 32, 64);

            if (q == 0) {
                float zi = 1.0f / fmaxf(z, 1e-16f);
                float4 res;
                res.x = fmaxf(fmaf(o.x * zi, S.x, C.x), 0.f);
                res.y = fmaxf(fmaf(o.y * zi, S.y, C.y), 0.f);
                res.z = fmaxf(fmaf(o.z * zi, S.z, C.z), 0.f);
                res.w = fmaxf(fmaf(o.w * zi, S.w, C.w), 0.f);
                *((float4*)&hT[w][kk][k4]) = res;   // contiguous b128, conflict-free
            }
        }

        // wave-local visibility of hT (same wave wrote it)
        asm volatile("s_waitcnt lgkmcnt(0)" ::: "memory");

        // ---- per-wave 8x128 mini-GEMM: xln/xrn rows for the batch ----
        v2f acc[8][2];
#pragma unroll
        for (int kk = 0; kk < 8; kk++) { acc[kk][0] = (v2f){0.f, 0.f}; acc[kk][1] = (v2f){0.f, 0.f}; }
#pragma unroll 4
        for (int j16 = 0; j16 < 32; j16++) {
            int j = jh * 32 + j16;
            float4 wv = *(const float4*)&sW[mat][j][k4];
            v2f w0 = {wv.x, wv.y}, w1 = {wv.z, wv.w};
            // uniform scalar broadcasts (free); pairs 256B apart -> ds_read2_b32
            MMROW(0, hT[w][0][j]); MMROW(1, hT[w][1][j]);
            MMROW(2, hT[w][2][j]); MMROW(3, hT[w][3][j]);
            MMROW(4, hT[w][4][j]); MMROW(5, hT[w][5][j]);
            MMROW(6, hT[w][6][j]); MMROW(7, hT[w][7][j]);
        }
#pragma unroll
        for (int kk = 0; kk < 8; kk++) {
            acc[kk][0].x += __shfl_xor(acc[kk][0].x, 16, 64);
            acc[kk][0].y += __shfl_xor(acc[kk][0].y, 16, 64);
            acc[kk][1].x += __shfl_xor(acc[kk][1].x, 16, 64);
            acc[kk][1].y += __shfl_xor(acc[kk][1].y, 16, 64);
        }
        if (jh == 0) {
            float* dstp = mat ? xrn : xln;
            float4 be = mat ? *(const float4*)(brn + k4) : *(const float4*)(bln + k4);
#pragma unroll
            for (int kk = 0; kk < 8; kk++) {
                if (kk < kmax) {
                    int nn = b0 + kk * NW;
                    float4 o4 = make_float4(acc[kk][0].x + be.x, acc[kk][0].y + be.y,
                                            acc[kk][1].x + be.z, acc[kk][1].y + be.w);
                    *((float4*)(dstp + (size_t)nn * 64 + k4)) = o4;
                }
            }
        }
    }
}

// ---------------- plain fused GATv2 (last layer, writes h) -------------------------

__global__ __launch_bounds__(256) void gat_fused12_kernel(
    const float* __restrict__ xl, const float* __restrict__ xr,
    const float4* __restrict__ recP, const int* __restrict__ cnt,
    const float* __restrict__ We, const float* __restrict__ att,
    const float* __restrict__ bo,
    const float* __restrict__ bn_g, const float* __restrict__ bn_b,
    const float* __restrict__ bn_m, const float* __restrict__ bn_v,
    float* __restrict__ hout) {
    int t = threadIdx.x;
    int w = t >> 6;
    int lane = t & 63;
    int q = lane >> 4;
    int r = lane & 15;
    int k4 = r * 4;

    float4 we0 = *(const float4*)(We + 0 * 64 + k4);
    float4 we1 = *(const float4*)(We + 64 + k4);
    float4 we2 = *(const float4*)(We + 128 + k4);
    float4 at4 = *(const float4*)(att + k4);
    v2f we0a = {we0.x, we0.y}, we0b = {we0.z, we0.w};
    v2f we1a = {we1.x, we1.y}, we1b = {we1.z, we1.w};
    v2f we2a = {we2.x, we2.y}, we2b = {we2.z, we2.w};
    v2f ata  = {at4.x, at4.y}, atb  = {at4.z, at4.w};
    float4 bo4 = *(const float4*)(bo + k4);
    float4 g4  = *(const float4*)(bn_g + k4);
    float4 b4  = *(const float4*)(bn_b + k4);
    float4 m4  = *(const float4*)(bn_m + k4);
    float4 v4  = *(const float4*)(bn_v + k4);
    float4 S, C;
    S.x = g4.x / sqrtf(v4.x + EPS_BN);  C.x = (bo4.x - m4.x) * S.x + b4.x;
    S.y = g4.y / sqrtf(v4.y + EPS_BN);  C.y = (bo4.y - m4.y) * S.y + b4.y;
    S.z = g4.z / sqrtf(v4.z + EPS_BN);  C.z = (bo4.z - m4.z) * S.z + b4.z;
    S.w = g4.w / sqrtf(v4.w + EPS_BN);  C.w = (bo4.w - m4.w) * S.w + b4.w;

    const int NW = gridDim.x * 4;
    for (int n0 = blockIdx.x * 4 + w; n0 < N_NODES; n0 += NW) {
        int n = __builtin_amdgcn_readfirstlane(n0);
        float4 xq = *(const float4*)(xr + (size_t)n * 64 + k4);
        v2f xra = {xq.x, xq.y}, xrb = {xq.z, xq.w};
        int beg = n * CAP;
        int end = beg + min(cnt[n], CAP);

        float4 cA0 = recP[beg + q];
        float4 cB0 = recP[beg + 4 + q];
        float4 cA1 = recP[beg + 8 + q];
        float4 cB1 = recP[beg + 12 + q];
        bool wA0 = (beg + q) < end,      wB0 = (beg + 4 + q) < end;
        bool wA1 = (beg + 8 + q) < end,  wB1 = (beg + 12 + q) < end;
        float4 gA0 = *(const float4*)(xl + (min((unsigned)__float_as_int(cA0.x), MAXOFF) + k4));
        float4 gB0 = *(const float4*)(xl + (min((unsigned)__float_as_int(cB0.x), MAXOFF) + k4));

        v2f oAa = {0.f, 0.f}, oAb = {0.f, 0.f};
        v2f oBa = {0.f, 0.f}, oBb = {0.f, 0.f};
        float zA = 0.f, zB = 0.f;

        int c = beg;
        while (c < end) {
            float4 gA1 = *(const float4*)(xl + (min((unsigned)__float_as_int(cA1.x), MAXOFF) + k4));
            float4 gB1 = *(const float4*)(xl + (min((unsigned)__float_as_int(cB1.x), MAXOFF) + k4));
            float4 cA2 = recP[c + 16 + q];
            float4 cB2 = recP[c + 20 + q];
            bool wA2 = (c + 16 + q) < end, wB2 = (c + 20 + q) < end;

            v2f xAa = {gA0.x, gA0.y}, xAb = {gA0.z, gA0.w};
            v2f xBa = {gB0.x, gB0.y}, xBb = {gB0.z, gB0.w};

            float accA, accB;
            EDGE_T(cA0, xAa, xAb, accA);
            EDGE_T(cB0, xBa, xBb, accB);

            accA += __shfl_xor(accA, 1, 64);  accB += __shfl_xor(accB, 1, 64);
            accA += __shfl_xor(accA, 2, 64);  accB += __shfl_xor(accB, 2, 64);
            accA += __shfl_xor(accA, 4, 64);  accB += __shfl_xor(accB, 4, 64);
            accA += __shfl_xor(accA, 8, 64);  accB += __shfl_xor(accB, 8, 64);

            float peA = wA0 ? __expf(accA) : 0.f;
            float peB = wB0 ? __expf(accB) : 0.f;
            v2f pAv = {peA, peA}, pBv = {peB, peB};
            oAa = __builtin_elementwise_fma(pAv, xAa, oAa);
            oAb = __builtin_elementwise_fma(pAv, xAb, oAb);
            oBa = __builtin_elementwise_fma(pBv, xBa, oBa);
            oBb = __builtin_elementwise_fma(pBv, xBb, oBb);
            zA += peA; zB += peB;

            cA0 = cA1; cB0 = cB1; wA0 = wA1; wB0 = wB1;
            cA1 = cA2; cB1 = cB2; wA1 = wA2; wB1 = wB2;
            gA0 = gA1; gB0 = gB1;
            c += 8;
        }

        v2f oa = oAa + oBa, ob = oAb + oBb;
        float z = zA + zB;
        float4 o = make_float4(oa.x, oa.y, ob.x, ob.y);
        o.x += __shfl_xor(o.x, 16, 64); o.x += __shfl_xor(o.x, 32, 64);
        o.y += __shfl_xor(o.y, 16, 64); o.y += __shfl_xor(o.y, 32, 64);
        o.z += __shfl_xor(o.z, 16, 64); o.z += __shfl_xor(o.z, 32, 64);
        o.w += __shfl_xor(o.w, 16, 64); o.w += __shfl_xor(o.w, 32, 64);
        z += __shfl_xor(z, 16, 64); z += __shfl_xor(z, 32, 64);

        if (q == 0) {
            float zi = 1.0f / fmaxf(z, 1e-16f);
            float4 res;
            res.x = fmaxf(fmaf(o.x * zi, S.x, C.x), 0.f);
            res.y = fmaxf(fmaf(o.y * zi, S.y, C.y), 0.f);
            res.z = fmaxf(fmaf(o.z * zi, S.z, C.z), 0.f);
            res.w = fmaxf(fmaf(o.w * zi, S.w, C.w), 0.f);
            *(float4*)(hout + (size_t)n * 64 + k4) = res;
        }
    }
}

// ---------------- readout: 4 waves/block, LDS cross-wave reduce ----------------

__global__ __launch_bounds__(256) void pool_all2_kernel(
    const float* __restrict__ h, const int* __restrict__ batch,
    const float* __restrict__ Wjk, const float* __restrict__ bjk,
    const float* __restrict__ Whead, const float* __restrict__ bhead,
    float* __restrict__ out) {
    __shared__ float red[4][64];
    int g = blockIdx.x;
    int t = threadIdx.x;
    int k = t & 63;
    int w = t >> 6;
    int lo = 0, hi = N_NODES;
    while (lo < hi) { int mid = (lo + hi) >> 1; if (batch[mid] < g) lo = mid + 1; else hi = mid; }
    int s = lo;
    hi = N_NODES;
    while (lo < hi) { int mid = (lo + hi) >> 1; if (batch[mid] < g + 1) lo = mid + 1; else hi = mid; }
    int e = lo;

    float acc = 0.f;
    for (int n = s + w; n < e; n += 4) acc += h[(size_t)n * 64 + k];
    red[w][k] = acc;
    __syncthreads();

    if (w == 0) {
        acc = (red[0][k] + red[1][k]) + (red[2][k] + red[3][k]);
        float wc = 0.f;
        for (int j = 0; j < 64; j++) wc = fmaf(Wjk[k * 64 + j], Whead[j], wc);
        float bc = bjk[k] * Whead[k];
        for (int off = 32; off > 0; off >>= 1) bc += __shfl_xor(bc, off, 64);
        float cntf = (float)(e - s);
        acc /= fmaxf(cntf, 1.0f);
        float v = acc * wc;
        for (int off = 32; off > 0; off >>= 1) v += __shfl_xor(v, off, 64);
        if (k == 0) out[g] = v + bc + bhead[0];
    }
}

// ---------------- launch ----------------

extern "C" void kernel_launch(void* const* d_in, const int* in_sizes, int n_in,
                              void* d_out, int out_size, void* d_ws, size_t ws_size,
                              hipStream_t stream) {
    const float* x     = (const float*)d_in[0];
    const float* ea    = (const float*)d_in[1];
    const float* Wl0   = (const float*)d_in[2];
    const float* Wr0   = (const float*)d_in[3];
    const float* bl0   = (const float*)d_in[4];
    const float* br0   = (const float*)d_in[5];
    const float* We0   = (const float*)d_in[6];
    const float* att0  = (const float*)d_in[7];
    const float* bo0   = (const float*)d_in[8];
    const float* Wl    = (const float*)d_in[9];
    const float* Wr    = (const float*)d_in[10];
    const float* bl    = (const float*)d_in[11];
    const float* br    = (const float*)d_in[12];
    const float* We    = (const float*)d_in[13];
    const float* att   = (const float*)d_in[14];
    const float* bo    = (const float*)d_in[15];
    const float* bn_g  = (const float*)d_in[16];
    const float* bn_b  = (const float*)d_in[17];
    const float* bn_m  = (const float*)d_in[18];
    const float* bn_v  = (const float*)d_in[19];
    const float* Wjk   = (const float*)d_in[20];
    const float* bjk   = (const float*)d_in[21];
    const float* Whead = (const float*)d_in[22];
    const float* bhead = (const float*)d_in[23];
    const int* edge_index = (const int*)d_in[24];
    const int* batch      = (const int*)d_in[25];

    const int* srcIdx = edge_index;            // edge_index[0]
    const int* dstIdx = edge_index + N_EDGES;  // edge_index[1]

    char* ws = (char*)d_ws;
    size_t off = 0;
    auto alloc = [&](size_t bytes) -> void* {
        void* p = ws + off;
        off += (bytes + 255) & ~(size_t)255;
        return p;
    };
    float* hbuf    = (float*)alloc((size_t)N_NODES * 64 * 4);
    float* xlA     = (float*)alloc((size_t)N_NODES * 64 * 4);
    float* xrA     = (float*)alloc((size_t)N_NODES * 64 * 4);
    float* xlB     = (float*)alloc((size_t)N_NODES * 64 * 4);
    float* xrB     = (float*)alloc((size_t)N_NODES * 64 * 4);
    int*   cnt     = (int*)alloc((size_t)N_NODES * 4);
    float4* recP   = (float4*)alloc(((size_t)N_NODES * CAP + 32) * 16);  // +32 slack records

    // ---- fused bucket build + layer-0 transform ----
    hipMemsetAsync(cnt, 0, (size_t)N_NODES * 4, stream);
    scatter_t9_kernel<<<(N_EDGES + 255) / 256, 256, 0, stream>>>(
        srcIdx, dstIdx, ea, cnt, recP, x, Wl0, bl0, Wr0, br0, xlA, xrA);

    const int GBF = 2048;    // gatT grid: 8192 waves -> one 8-node batch per wave
    const int GB  = 2048;    // last-layer gat grid

    // ---- layers 0..3: gat + fused next-layer transform ----
    gat_fusedT_kernel<<<GBF, 256, 0, stream>>>(xlA, xrA, recP, cnt,
        We0, att0, bo0, bn_g, bn_b, bn_m, bn_v,
        Wl, bl, Wr, br, xlB, xrB);
    for (int i = 1; i < 4; i++) {
        const float* xin  = (i & 1) ? xlB : xlA;
        const float* xrin = (i & 1) ? xrB : xrA;
        float* xout  = (i & 1) ? xlA : xlB;
        float* xrout = (i & 1) ? xrA : xrB;
        gat_fusedT_kernel<<<GBF, 256, 0, stream>>>(xin, xrin, recP, cnt,
            We + (size_t)(i - 1) * 3 * 64, att + (size_t)(i - 1) * 64,
            bo + (size_t)(i - 1) * 64,
            bn_g + (size_t)i * 64, bn_b + (size_t)i * 64,
            bn_m + (size_t)i * 64, bn_v + (size_t)i * 64,
            Wl + (size_t)i * 64 * 64, bl + (size_t)i * 64,
            Wr + (size_t)i * 64 * 64, br + (size_t)i * 64,
            xout, xrout);
    }

    // ---- layer 4: plain gat -> h ----
    gat_fused12_kernel<<<GB, 256, 0, stream>>>(xlA, xrA, recP, cnt,
        We + (size_t)3 * 3 * 64, att + (size_t)3 * 64, bo + (size_t)3 * 64,
        bn_g + (size_t)4 * 64, bn_b + (size_t)4 * 64,
        bn_m + (size_t)4 * 64, bn_v + (size_t)4 * 64,
        hbuf);

    // ---- readout ----
    pool_all2_kernel<<<N_GRAPHS, 256, 0, stream>>>(hbuf, batch, Wjk, bjk, Whead, bhead,
                                                   (float*)d_out);
}

// Round 9
// 447.131 us; speedup vs baseline: 1.0702x; 1.0702x over previous
//
#include <hip/hip_runtime.h>
#include <math.h>

#define N_NODES 50000
#define N_EDGES 800000
#define N_GRAPHS 512
#define SLOPE 0.2f
#define CAP 48   // bucket capacity; degrees ~Poisson(16), P(deg>48)~1e-11
static constexpr float EPS_BN = 1e-5f;
static constexpr unsigned MAXOFF = (N_NODES - 1) * 64;  // clamp for garbage-slot gathers

typedef float v2f __attribute__((ext_vector_type(2)));

// ---------------- fused bucket-scatter + layer-0 transform (known-good t9) ----------
// ~57 us = atomic-chain floor at max TLP (tested EPT 1/2/4); accepted.

__global__ __launch_bounds__(256) void scatter_t9_kernel(
    const int* __restrict__ src, const int* __restrict__ dst,
    const float* __restrict__ ea,
    int* __restrict__ cnt, float4* __restrict__ rec,
    const float* __restrict__ x,
    const float* __restrict__ Wl0, const float* __restrict__ bl0,
    const float* __restrict__ Wr0, const float* __restrict__ br0,
    float* __restrict__ xl, float* __restrict__ xr) {
    int t = threadIdx.x;
    int e = blockIdx.x * 256 + t;
    if (e < N_EDGES) {
        int d = dst[e];
        int pos = atomicAdd(&cnt[d], 1);
        if (pos < CAP)
            rec[(size_t)d * CAP + pos] = make_float4(__int_as_float(src[e] * 64),
                                                     ea[e * 3 + 0], ea[e * 3 + 1], ea[e * 3 + 2]);
    }

    int w = t >> 6;
    int k = t & 63;
    v2f wlr[9];
#pragma unroll
    for (int j = 0; j < 9; j++) wlr[j] = (v2f){Wl0[j * 64 + k], Wr0[j * 64 + k]};
    v2f bias = {bl0[k], br0[k]};
    const int NW = gridDim.x * 4;
    for (int n = blockIdx.x * 4 + w; n < N_NODES; n += NW) {
        int un = __builtin_amdgcn_readfirstlane(n);
        const float* __restrict__ hrow = x + (size_t)un * 9;
        float hb[9];
#pragma unroll
        for (int j = 0; j < 9; j++) hb[j] = hrow[j];
        v2f acc = bias;
#pragma unroll
        for (int j = 0; j < 9; j++)
            acc = __builtin_elementwise_fma((v2f){hb[j], hb[j]}, wlr[j], acc);
        xl[(size_t)un * 64 + k] = acc.x;
        xr[(size_t)un * 64 + k] = acc.y;
    }
}

// ---------------- main transform (K=64): LDS-tiled GEMM (round-2 known-good) ------

__global__ __launch_bounds__(256) void transform6_kernel(
    const float* __restrict__ h,
    const float* __restrict__ Wl, const float* __restrict__ bl,
    const float* __restrict__ Wr, const float* __restrict__ br,
    float* __restrict__ xl, float* __restrict__ xr) {
    __shared__ float sAt[64][68];
    __shared__ float sB[64][128];
    int t = threadIdx.x;
    int n0 = blockIdx.x * 64;

#pragma unroll
    for (int i = 0; i < 4; i++) {
        int idx = i * 256 + t;
        int row = idx >> 4;
        int fc  = idx & 15;
        int n = n0 + row;
        float4 v = (n < N_NODES) ? *((const float4*)(h + (size_t)n * 64 + fc * 4))
                                 : make_float4(0.f, 0.f, 0.f, 0.f);
        sAt[fc * 4 + 0][row] = v.x;
        sAt[fc * 4 + 1][row] = v.y;
        sAt[fc * 4 + 2][row] = v.z;
        sAt[fc * 4 + 3][row] = v.w;
    }
#pragma unroll
    for (int i = 0; i < 8; i++) {
        int idx = i * 256 + t;
        int j  = idx >> 5;
        int fc = idx & 31;
        int c  = fc * 4;
        float4 v = (c < 64) ? *((const float4*)(Wl + j * 64 + c))
                            : *((const float4*)(Wr + j * 64 + (c - 64)));
        *((float4*)&sB[j][c]) = v;
    }
    __syncthreads();

    int tx = t & 15, ty = t >> 4;
    int c0 = tx * 4;
    float4 bls = *((const float4*)(bl + c0));
    float4 brs = *((const float4*)(br + c0));
    v2f acc[4][4];
#pragma unroll
    for (int r = 0; r < 4; r++) {
        acc[r][0] = (v2f){bls.x, bls.y};
        acc[r][1] = (v2f){bls.z, bls.w};
        acc[r][2] = (v2f){brs.x, brs.y};
        acc[r][3] = (v2f){brs.z, brs.w};
    }

#pragma unroll 4
    for (int j = 0; j < 64; j++) {
        float a0 = sAt[j][ty * 4 + 0];
        float a1 = sAt[j][ty * 4 + 1];
        float a2 = sAt[j][ty * 4 + 2];
        float a3 = sAt[j][ty * 4 + 3];
        float4 bq0 = *((const float4*)&sB[j][c0]);        // Wl cols c0..c0+3
        float4 bq1 = *((const float4*)&sB[j][64 + c0]);   // Wr cols c0..c0+3
        v2f b0 = {bq0.x, bq0.y}, b1 = {bq0.z, bq0.w};
        v2f b2 = {bq1.x, bq1.y}, b3 = {bq1.z, bq1.w};
        v2f a0v = {a0, a0}, a1v = {a1, a1}, a2v = {a2, a2}, a3v = {a3, a3};
        acc[0][0] = __builtin_elementwise_fma(a0v, b0, acc[0][0]);
        acc[0][1] = __builtin_elementwise_fma(a0v, b1, acc[0][1]);
        acc[0][2] = __builtin_elementwise_fma(a0v, b2, acc[0][2]);
        acc[0][3] = __builtin_elementwise_fma(a0v, b3, acc[0][3]);
        acc[1][0] = __builtin_elementwise_fma(a1v, b0, acc[1][0]);
        acc[1][1] = __builtin_elementwise_fma(a1v, b1, acc[1][1]);
        acc[1][2] = __builtin_elementwise_fma(a1v, b2, acc[1][2]);
        acc[1][3] = __builtin_elementwise_fma(a1v, b3, acc[1][3]);
        acc[2][0] = __builtin_elementwise_fma(a2v, b0, acc[2][0]);
        acc[2][1] = __builtin_elementwise_fma(a2v, b1, acc[2][1]);
        acc[2][2] = __builtin_elementwise_fma(a2v, b2, acc[2][2]);
        acc[2][3] = __builtin_elementwise_fma(a2v, b3, acc[2][3]);
        acc[3][0] = __builtin_elementwise_fma(a3v, b0, acc[3][0]);
        acc[3][1] = __builtin_elementwise_fma(a3v, b1, acc[3][1]);
        acc[3][2] = __builtin_elementwise_fma(a3v, b2, acc[3][2]);
        acc[3][3] = __builtin_elementwise_fma(a3v, b3, acc[3][3]);
    }

#pragma unroll
    for (int r = 0; r < 4; r++) {
        int n = n0 + ty * 4 + r;
        if (n < N_NODES) {
            *((float4*)(xl + (size_t)n * 64 + c0)) =
                make_float4(acc[r][0].x, acc[r][0].y, acc[r][1].x, acc[r][1].y);
            *((float4*)(xr + (size_t)n * 64 + c0)) =
                make_float4(acc[r][2].x, acc[r][2].y, acc[r][3].x, acc[r][3].y);
        }
    }
}

// ---------------- fused GATv2 layer: CAP fully unrolled (6 blocks of 8) ------------
// No edge loop at all: super-block 0 (edges 0..15) always, SB1 (16..31) if deg>16
// (43%), SB2 (32..47) if deg>32 (P~6e-5). Kills the per-iteration rotation movs +
// bookkeeping of the pipelined loop and keeps 4 gathers + 4 rec loads in flight.
// All rec reads stay inside the node's own CAP=48 bucket -> unguarded is safe;
// garbage offsets clamped to MAXOFF, garbage lanes masked at exp (select).

#define EDGE_T(rX, xXa, xXb, accX)                                        \
    {                                                                     \
        v2f tXa = xXa + xra, tXb = xXb + xrb;                             \
        tXa = __builtin_elementwise_fma((v2f){rX.y, rX.y}, we0a, tXa);    \
        tXb = __builtin_elementwise_fma((v2f){rX.y, rX.y}, we0b, tXb);    \
        tXa = __builtin_elementwise_fma((v2f){rX.z, rX.z}, we1a, tXa);    \
        tXb = __builtin_elementwise_fma((v2f){rX.z, rX.z}, we1b, tXb);    \
        tXa = __builtin_elementwise_fma((v2f){rX.w, rX.w}, we2a, tXa);    \
        tXb = __builtin_elementwise_fma((v2f){rX.w, rX.w}, we2b, tXb);    \
        tXa = __builtin_elementwise_max(tXa, tXa * SLOPE);                \
        tXb = __builtin_elementwise_max(tXb, tXb * SLOPE);                \
        v2f dX = ata * tXa;                                               \
        dX = __builtin_elementwise_fma(atb, tXb, dX);                     \
        accX = dX.x + dX.y;                                               \
    }

#define GATHER(rX) (*(const float4*)(xl + (min((unsigned)__float_as_int(rX.x), MAXOFF) + k4)))

// computes 8 edges: quad A at slots off+q, quad B at slots off+4+q
#define COMPUTE8(cA, gA, cB, gB, off)                                      \
    {                                                                      \
        bool wA = (off + q) < cn;                                          \
        bool wB = (off + 4 + q) < cn;                                      \
        v2f xAa = {gA.x, gA.y}, xAb = {gA.z, gA.w};                        \
        v2f xBa = {gB.x, gB.y}, xBb = {gB.z, gB.w};                        \
        float accA, accB;                                                  \
        EDGE_T(cA, xAa, xAb, accA);                                        \
        EDGE_T(cB, xBa, xBb, accB);                                        \
        accA += __shfl_xor(accA, 1, 64);  accB += __shfl_xor(accB, 1, 64); \
        accA += __shfl_xor(accA, 2, 64);  accB += __shfl_xor(accB, 2, 64); \
        accA += __shfl_xor(accA, 4, 64);  accB += __shfl_xor(accB, 4, 64); \
        accA += __shfl_xor(accA, 8, 64);  accB += __shfl_xor(accB, 8, 64); \
        float peA = wA ? __expf(accA) : 0.f;                               \
        float peB = wB ? __expf(accB) : 0.f;                               \
        v2f pAv = {peA, peA}, pBv = {peB, peB};                            \
        oAa = __builtin_elementwise_fma(pAv, xAa, oAa);                    \
        oAb = __builtin_elementwise_fma(pAv, xAb, oAb);                    \
        oBa = __builtin_elementwise_fma(pBv, xBa, oBa);                    \
        oBb = __builtin_elementwise_fma(pBv, xBb, oBb);                    \
        zA += peA; zB += peB;                                              \
    }

__global__ __launch_bounds__(256) void gat_fused13_kernel(
    const float* __restrict__ xl, const float* __restrict__ xr,
    const float4* __restrict__ recP, const int* __restrict__ cnt,
    const float* __restrict__ We, const float* __restrict__ att,
    const float* __restrict__ bo,
    const float* __restrict__ bn_g, const float* __restrict__ bn_b,
    const float* __restrict__ bn_m, const float* __restrict__ bn_v,
    float* __restrict__ hout) {
    int t = threadIdx.x;
    int w = t >> 6;
    int lane = t & 63;
    int q = lane >> 4;
    int r = lane & 15;
    int k4 = r * 4;

    // layer-invariant constants
    float4 we0 = *(const float4*)(We + 0 * 64 + k4);
    float4 we1 = *(const float4*)(We + 64 + k4);
    float4 we2 = *(const float4*)(We + 128 + k4);
    float4 at4 = *(const float4*)(att + k4);
    v2f we0a = {we0.x, we0.y}, we0b = {we0.z, we0.w};
    v2f we1a = {we1.x, we1.y}, we1b = {we1.z, we1.w};
    v2f we2a = {we2.x, we2.y}, we2b = {we2.z, we2.w};
    v2f ata  = {at4.x, at4.y}, atb  = {at4.z, at4.w};
    // fold bias+BN into res = max(o*zi*S + C, 0)
    float4 bo4 = *(const float4*)(bo + k4);
    float4 g4  = *(const float4*)(bn_g + k4);
    float4 b4  = *(const float4*)(bn_b + k4);
    float4 m4  = *(const float4*)(bn_m + k4);
    float4 v4  = *(const float4*)(bn_v + k4);
    float4 S, C;
    S.x = g4.x / sqrtf(v4.x + EPS_BN);  C.x = (bo4.x - m4.x) * S.x + b4.x;
    S.y = g4.y / sqrtf(v4.y + EPS_BN);  C.y = (bo4.y - m4.y) * S.y + b4.y;
    S.z = g4.z / sqrtf(v4.z + EPS_BN);  C.z = (bo4.z - m4.z) * S.z + b4.z;
    S.w = g4.w / sqrtf(v4.w + EPS_BN);  C.w = (bo4.w - m4.w) * S.w + b4.w;

    const int NW = gridDim.x * 4;
    for (int n0 = blockIdx.x * 4 + w; n0 < N_NODES; n0 += NW) {
        int n = __builtin_amdgcn_readfirstlane(n0);
        int beg = n * CAP;
        int cn = min(cnt[n], CAP);
        float4 xq = *(const float4*)(xr + (size_t)n * 64 + k4);
        v2f xra = {xq.x, xq.y}, xrb = {xq.z, xq.w};

        // super-block 0: recs 0..15 + their gathers; prefetch recs 16..31
        float4 r0 = recP[beg + q];
        float4 r1 = recP[beg + 4 + q];
        float4 r2 = recP[beg + 8 + q];
        float4 r3 = recP[beg + 12 + q];
        float4 r4 = recP[beg + 16 + q];
        float4 r5 = recP[beg + 20 + q];
        float4 r6 = recP[beg + 24 + q];
        float4 r7 = recP[beg + 28 + q];
        float4 g0 = GATHER(r0);
        float4 g1 = GATHER(r1);
        float4 g2 = GATHER(r2);
        float4 g3 = GATHER(r3);

        v2f oAa = {0.f, 0.f}, oAb = {0.f, 0.f};
        v2f oBa = {0.f, 0.f}, oBb = {0.f, 0.f};
        float zA = 0.f, zB = 0.f;

        COMPUTE8(r0, g0, r1, g1, 0);
        COMPUTE8(r2, g2, r3, g3, 8);

        if (cn > 16) {           // 43% of nodes (wave-uniform branch)
            float4 g4_ = GATHER(r4);
            float4 g5_ = GATHER(r5);
            float4 g6_ = GATHER(r6);
            float4 g7_ = GATHER(r7);
            COMPUTE8(r4, g4_, r5, g5_, 16);
            COMPUTE8(r6, g6_, r7, g7_, 24);

            if (cn > 32) {       // P ~ 6e-5: latency here is irrelevant
                float4 r8  = recP[beg + 32 + q];
                float4 r9  = recP[beg + 36 + q];
                float4 r10 = recP[beg + 40 + q];
                float4 r11 = recP[beg + 44 + q];
                float4 g8  = GATHER(r8);
                float4 g9  = GATHER(r9);
                float4 g10 = GATHER(r10);
                float4 g11 = GATHER(r11);
                COMPUTE8(r8, g8, r9, g9, 32);
                COMPUTE8(r10, g10, r11, g11, 40);
            }
        }

        v2f oa = oAa + oBa, ob = oAb + oBb;
        float z = zA + zB;
        float4 o = make_float4(oa.x, oa.y, ob.x, ob.y);
        o.x += __shfl_xor(o.x, 16, 64); o.x += __shfl_xor(o.x, 32, 64);
        o.y += __shfl_xor(o.y, 16, 64); o.y += __shfl_xor(o.y, 32, 64);
        o.z += __shfl_xor(o.z, 16, 64); o.z += __shfl_xor(o.z, 32, 64);
        o.w += __shfl_xor(o.w, 16, 64); o.w += __shfl_xor(o.w, 32, 64);
        z += __shfl_xor(z, 16, 64); z += __shfl_xor(z, 32, 64);

        if (q == 0) {
            float zi = 1.0f / fmaxf(z, 1e-16f);
            float4 res;
            res.x = fmaxf(fmaf(o.x * zi, S.x, C.x), 0.f);
            res.y = fmaxf(fmaf(o.y * zi, S.y, C.y), 0.f);
            res.z = fmaxf(fmaf(o.z * zi, S.z, C.z), 0.f);
            res.w = fmaxf(fmaf(o.w * zi, S.w, C.w), 0.f);
            *(float4*)(hout + (size_t)n * 64 + k4) = res;
        }
    }
}

// ---------------- readout: 4 waves/block, LDS cross-wave reduce ----------------

__global__ __launch_bounds__(256) void pool_all2_kernel(
    const float* __restrict__ h, const int* __restrict__ batch,
    const float* __restrict__ Wjk, const float* __restrict__ bjk,
    const float* __restrict__ Whead, const float* __restrict__ bhead,
    float* __restrict__ out) {
    __shared__ float red[4][64];
    int g = blockIdx.x;
    int t = threadIdx.x;
    int k = t & 63;
    int w = t >> 6;
    int lo = 0, hi = N_NODES;
    while (lo < hi) { int mid = (lo + hi) >> 1; if (batch[mid] < g) lo = mid + 1; else hi = mid; }
    int s = lo;
    hi = N_NODES;
    while (lo < hi) { int mid = (lo + hi) >> 1; if (batch[mid] < g + 1) lo = mid + 1; else hi = mid; }
    int e = lo;

    float acc = 0.f;
    for (int n = s + w; n < e; n += 4) acc += h[(size_t)n * 64 + k];
    red[w][k] = acc;
    __syncthreads();

    if (w == 0) {
        acc = (red[0][k] + red[1][k]) + (red[2][k] + red[3][k]);
        float wc = 0.f;
        for (int j = 0; j < 64; j++) wc = fmaf(Wjk[k * 64 + j], Whead[j], wc);
        float bc = bjk[k] * Whead[k];
        for (int off = 32; off > 0; off >>= 1) bc += __shfl_xor(bc, off, 64);
        float cntf = (float)(e - s);
        acc /= fmaxf(cntf, 1.0f);
        float v = acc * wc;
        for (int off = 32; off > 0; off >>= 1) v += __shfl_xor(v, off, 64);
        if (k == 0) out[g] = v + bc + bhead[0];
    }
}

// ---------------- launch ----------------

extern "C" void kernel_launch(void* const* d_in, const int* in_sizes, int n_in,
                              void* d_out, int out_size, void* d_ws, size_t ws_size,
                              hipStream_t stream) {
    const float* x     = (const float*)d_in[0];
    const float* ea    = (const float*)d_in[1];
    const float* Wl0   = (const float*)d_in[2];
    const float* Wr0   = (const float*)d_in[3];
    const float* bl0   = (const float*)d_in[4];
    const float* br0   = (const float*)d_in[5];
    const float* We0   = (const float*)d_in[6];
    const float* att0  = (const float*)d_in[7];
    const float* bo0   = (const float*)d_in[8];
    const float* Wl    = (const float*)d_in[9];
    const float* Wr    = (const float*)d_in[10];
    const float* bl    = (const float*)d_in[11];
    const float* br    = (const float*)d_in[12];
    const float* We    = (const float*)d_in[13];
    const float* att   = (const float*)d_in[14];
    const float* bo    = (const float*)d_in[15];
    const float* bn_g  = (const float*)d_in[16];
    const float* bn_b  = (const float*)d_in[17];
    const float* bn_m  = (const float*)d_in[18];
    const float* bn_v  = (const float*)d_in[19];
    const float* Wjk   = (const float*)d_in[20];
    const float* bjk   = (const float*)d_in[21];
    const float* Whead = (const float*)d_in[22];
    const float* bhead = (const float*)d_in[23];
    const int* edge_index = (const int*)d_in[24];
    const int* batch      = (const int*)d_in[25];

    const int* srcIdx = edge_index;            // edge_index[0]
    const int* dstIdx = edge_index + N_EDGES;  // edge_index[1]

    char* ws = (char*)d_ws;
    size_t off = 0;
    auto alloc = [&](size_t bytes) -> void* {
        void* p = ws + off;
        off += (bytes + 255) & ~(size_t)255;
        return p;
    };
    float* hA      = (float*)alloc((size_t)N_NODES * 64 * 4);
    float* hB      = (float*)alloc((size_t)N_NODES * 64 * 4);
    float* xlb     = (float*)alloc((size_t)N_NODES * 64 * 4);
    float* xrb     = (float*)alloc((size_t)N_NODES * 64 * 4);
    int*   cnt     = (int*)alloc((size_t)N_NODES * 4);
    float4* recP   = (float4*)alloc((size_t)N_NODES * CAP * 16);  // 38.4 MB

    // ---- fused bucket build + layer-0 transform ----
    hipMemsetAsync(cnt, 0, (size_t)N_NODES * 4, stream);
    scatter_t9_kernel<<<(N_EDGES + 255) / 256, 256, 0, stream>>>(
        srcIdx, dstIdx, ea, cnt, recP, x, Wl0, bl0, Wr0, br0, xlb, xrb);

    const int GB  = 2048;                      // gat grid: grid-stride, ~6 nodes/wave
    const int NBG = (N_NODES + 63) / 64;       // 782 (GEMM transform grid)

    // ---- layer 0 GAT ----
    gat_fused13_kernel<<<GB, 256, 0, stream>>>(xlb, xrb, recP, cnt,
                                               We0, att0, bo0,
                                               bn_g, bn_b, bn_m, bn_v, hA);

    // ---- layers 1..4 ----
    float* hcur = hA;
    float* hnext = hB;
    for (int i = 0; i < 4; i++) {
        transform6_kernel<<<NBG, 256, 0, stream>>>(hcur,
            Wl + (size_t)i * 64 * 64, bl + (size_t)i * 64,
            Wr + (size_t)i * 64 * 64, br + (size_t)i * 64,
            xlb, xrb);
        gat_fused13_kernel<<<GB, 256, 0, stream>>>(xlb, xrb, recP, cnt,
            We + (size_t)i * 3 * 64, att + (size_t)i * 64,
            bo + (size_t)i * 64,
            bn_g + (size_t)(i + 1) * 64, bn_b + (size_t)(i + 1) * 64,
            bn_m + (size_t)(i + 1) * 64, bn_v + (size_t)(i + 1) * 64,
            hnext);
        float* tp = hcur; hcur = hnext; hnext = tp;
    }

    // ---- readout ----
    pool_all2_kernel<<<N_GRAPHS, 256, 0, stream>>>(hcur, batch, Wjk, bjk, Whead, bhead,
                                                   (float*)d_out);
}